// Round 4
// baseline (300.048 us; speedup 1.0000x reference)
//
#include <hip/hip_runtime.h>

// GeodesicAttentionBlock fused kernel, fp32 inputs -> fp32 output, MI355X gfx950.
// Strategy: prep kernel folds (Wq - Wk) and L into Wd[2048][256] (bf16) so that
//   diff_t[b,q,k,f] = x . Wd[:,(q,k,f)]  (one dense GEMM, no Q/K/diff materialization)
// Main kernel: per block 64 rows, 512 threads (8 waves, wave = q-head).
//   stage x (fp32->bf16) -> V GEMM -> Wd GEMM + square-reduce epilogue ->
//   softmax + attnV -> Wout GEMM + bias + fp32 residual -> fp32 LN -> fp32 store.

typedef __bf16 bf16x8 __attribute__((ext_vector_type(8)));
typedef float  f32x4  __attribute__((ext_vector_type(4)));
typedef int    i32x4  __attribute__((ext_vector_type(4)));
typedef unsigned short u16;

__device__ __forceinline__ float bf2f(u16 u){
  unsigned int x = ((unsigned int)u) << 16;
  return __builtin_bit_cast(float, x);
}
__device__ __forceinline__ u16 f2bf(float f){
  unsigned int u = __builtin_bit_cast(unsigned int, f);
  u += 0x7FFFu + ((u >> 16) & 1u);          // round-to-nearest-even
  return (u16)(u >> 16);
}
__device__ __forceinline__ unsigned int pk2(float lo, float hi){
  return ((unsigned int)f2bf(hi) << 16) | (unsigned int)f2bf(lo);
}
__device__ __forceinline__ bf16x8 ldfrag(const u16* p){
  return __builtin_bit_cast(bf16x8, *(const i32x4*)p);
}

#define LROW 264   // padded bf16 LDS row (256 + 8): breaks 512B-stride bank conflicts
#define HROW 260   // padded fp32 LDS row for h

// ---------------- prep: build Wd, WvT, WoutT (bf16) in workspace ----------------
// ws layout (u16 elems): Wd [2048][256] @0 ; WvT [256][256] @524288 ; WoutT @589824
__global__ __launch_bounds__(256) void geo_prep(
    const float* __restrict__ Wq, const float* __restrict__ Wk,
    const float* __restrict__ Wv, const float* __restrict__ Wout,
    const float* __restrict__ L, u16* __restrict__ ws)
{
  u16* Wd    = ws;
  u16* WvT   = ws + 524288;
  u16* WoutT = ws + 589824;
  const int b = blockIdx.x, t = threadIdx.x;

  if (b < 64){
    // block (q,k): Wd[(q*256 + k*32 + f)][c] = sum_d (Wq[c][q*32+d]-Wk[c][k*32+d]) * L[k][d][f]
    const int q = b >> 3, k = b & 7;
    __shared__ float dwb[256][33];
    __shared__ float Lk[32][33];
    for (int i = 0; i < 4; ++i){
      int idx = t + i*256;                       // 1024 elems of L[k]
      Lk[idx >> 5][idx & 31] = L[k*1024 + idx];
    }
    {
      const int c = t;
      const float* wqp = Wq + c*256 + q*32;
      const float* wkp = Wk + c*256 + k*32;
      #pragma unroll
      for (int j = 0; j < 8; ++j){
        f32x4 a  = *(const f32x4*)(wqp + j*4);
        f32x4 bb = *(const f32x4*)(wkp + j*4);
        #pragma unroll
        for (int p = 0; p < 4; ++p) dwb[c][j*4 + p] = a[p] - bb[p];
      }
    }
    __syncthreads();
    const int c = t;
    float wreg[32];
    #pragma unroll
    for (int d = 0; d < 32; ++d) wreg[d] = dwb[c][d];
    for (int f = 0; f < 32; ++f){
      float s = 0.f;
      #pragma unroll
      for (int d = 0; d < 32; ++d) s = fmaf(wreg[d], Lk[d][f], s);
      Wd[(size_t)(q*256 + k*32 + f)*256 + c] = f2bf(s);   // coalesced over c
    }
  } else {
    // transpose Wv / Wout into bf16 [n][c] layout, 64x64 tiles
    const int bb  = b - 64;
    const float* src = (bb < 16) ? Wv  : Wout;
    u16*         dst = (bb < 16) ? WvT : WoutT;
    const int tile = bb & 15;
    const int tr = tile >> 2, tc = tile & 3;
    __shared__ float tlf[64][68];
    {
      const int row = t >> 2, cs = (t & 3)*16;
      #pragma unroll
      for (int j = 0; j < 4; ++j){
        f32x4 v = *(const f32x4*)(src + (size_t)(tr*64 + row)*256 + tc*64 + cs + j*4);
        #pragma unroll
        for (int p = 0; p < 4; ++p) tlf[row][cs + j*4 + p] = v[p];
      }
    }
    __syncthreads();
    {
      const int n = t >> 2, cs = (t & 3)*16;
      float us[16];
      #pragma unroll
      for (int j = 0; j < 16; ++j) us[j] = tlf[cs + j][n];
      #pragma unroll
      for (int h = 0; h < 2; ++h){
        i32x4 o;
        #pragma unroll
        for (int p = 0; p < 4; ++p)
          o[p] = (int)pk2(us[h*8 + 2*p], us[h*8 + 2*p + 1]);
        *(i32x4*)(dst + (size_t)(tc*64 + n)*256 + tr*64 + cs + h*8) = o;
      }
    }
  }
}

// ---------------- main fused kernel ----------------
__global__ __launch_bounds__(512) void geo_fused(
    const float* __restrict__ x,   const u16* __restrict__ Wd,
    const u16* __restrict__ WvT,   const u16* __restrict__ WoutT,
    const float* __restrict__ b_out, const float* __restrict__ gamma,
    const float* __restrict__ beta,  float* __restrict__ out)
{
  // LDS pool with overlays:
  //   xs  bf16[64][264] @0        (33792 B)   x tile, dead after sq-GEMM
  //   Vs  bf16[64][264] @33792    (33792 B)   V, dead after attnV
  //   ao  bf16[64][264] @67584    (33792 B)   attention output
  //   sqs f32 [64][8][12] @101376 (24576 B)   sq_dist
  //   hs  f32 [64][260] @0        (66560 B)   h, overlays xs+Vs
  __shared__ __align__(16) char pool[125952];
  u16  (*xs)[LROW]   = (u16 (*)[LROW])(pool);
  u16  (*Vs)[LROW]   = (u16 (*)[LROW])(pool + 33792);
  u16  (*ao)[LROW]   = (u16 (*)[LROW])(pool + 67584);
  float (*sqs)[8][12] = (float (*)[8][12])(pool + 101376);
  float (*hs)[HROW]  = (float (*)[HROW])(pool);

  const int t    = threadIdx.x;
  const int lane = t & 63;
  const int w    = t >> 6;           // wave 0..7 == q-head
  const int l15  = lane & 15;
  const int quad = lane >> 4;
  const long rowbase = (long)blockIdx.x * 64;

  // ---- stage x tile: fp32 loads, RNE pack to bf16 LDS ----
  {
    const int r  = t >> 3;
    const int c0 = (t & 7) * 32;
    const float* src = x + (rowbase + r)*256 + c0;
    unsigned int words[16];
    #pragma unroll
    for (int j = 0; j < 8; ++j){
      f32x4 v = *(const f32x4*)(src + j*4);
      words[j*2    ] = pk2(v[0], v[1]);
      words[j*2 + 1] = pk2(v[2], v[3]);
    }
    #pragma unroll
    for (int qd = 0; qd < 4; ++qd){
      i32x4 o;
      #pragma unroll
      for (int p = 0; p < 4; ++p) o[p] = (int)words[qd*4 + p];
      *(i32x4*)&xs[r][c0 + qd*8] = o;
    }
  }
  __syncthreads();

  // ---- V = x @ Wv : wave w covers cols [32w, 32w+32) ----
  {
    f32x4 acc[4][2];
    #pragma unroll
    for (int mt = 0; mt < 4; ++mt)
      #pragma unroll
      for (int nt = 0; nt < 2; ++nt) acc[mt][nt] = f32x4{0.f,0.f,0.f,0.f};
    #pragma unroll
    for (int kk = 0; kk < 8; ++kk){
      const int c0 = kk*32 + quad*8;
      bf16x8 a[4], bfr[2];
      #pragma unroll
      for (int mt = 0; mt < 4; ++mt) a[mt] = ldfrag(&xs[mt*16 + l15][c0]);
      #pragma unroll
      for (int nt = 0; nt < 2; ++nt){
        const int n = w*32 + nt*16 + l15;
        bfr[nt] = __builtin_bit_cast(bf16x8, *(const i32x4*)(WvT + (size_t)n*256 + c0));
      }
      #pragma unroll
      for (int mt = 0; mt < 4; ++mt)
        #pragma unroll
        for (int nt = 0; nt < 2; ++nt)
          acc[mt][nt] = __builtin_amdgcn_mfma_f32_16x16x32_bf16(a[mt], bfr[nt], acc[mt][nt], 0, 0, 0);
    }
    #pragma unroll
    for (int mt = 0; mt < 4; ++mt)
      #pragma unroll
      for (int nt = 0; nt < 2; ++nt){
        const int col = w*32 + nt*16 + l15;
        #pragma unroll
        for (int reg = 0; reg < 4; ++reg)
          Vs[mt*16 + quad*4 + reg][col] = f2bf(acc[mt][nt][reg]);
      }
  }

  // ---- sq_dist: D = Wd @ x^T, f lands in-lane -> cheap square-reduce ----
  {
    #pragma unroll
    for (int kp = 0; kp < 4; ++kp){
      f32x4 acc[2][2][4];   // [k2][mt(f-half)][nt(row-tile)]
      #pragma unroll
      for (int k2 = 0; k2 < 2; ++k2)
        #pragma unroll
        for (int mt = 0; mt < 2; ++mt)
          #pragma unroll
          for (int nt = 0; nt < 4; ++nt) acc[k2][mt][nt] = f32x4{0.f,0.f,0.f,0.f};
      #pragma unroll
      for (int kk = 0; kk < 8; ++kk){
        const int c0 = kk*32 + quad*8;
        bf16x8 bfr[4];
        #pragma unroll
        for (int nt = 0; nt < 4; ++nt) bfr[nt] = ldfrag(&xs[nt*16 + l15][c0]);
        bf16x8 a[2][2];
        #pragma unroll
        for (int k2 = 0; k2 < 2; ++k2)
          #pragma unroll
          for (int mt = 0; mt < 2; ++mt){
            const int m = w*256 + (kp*2 + k2)*32 + mt*16 + l15;
            a[k2][mt] = __builtin_bit_cast(bf16x8, *(const i32x4*)(Wd + (size_t)m*256 + c0));
          }
        #pragma unroll
        for (int k2 = 0; k2 < 2; ++k2)
          #pragma unroll
          for (int mt = 0; mt < 2; ++mt)
            #pragma unroll
            for (int nt = 0; nt < 4; ++nt)
              acc[k2][mt][nt] = __builtin_amdgcn_mfma_f32_16x16x32_bf16(a[k2][mt], bfr[nt], acc[k2][mt][nt], 0, 0, 0);
      }
      #pragma unroll
      for (int k2 = 0; k2 < 2; ++k2){
        const int k = kp*2 + k2;
        #pragma unroll
        for (int nt = 0; nt < 4; ++nt){
          float s = 0.f;
          #pragma unroll
          for (int mt = 0; mt < 2; ++mt)
            #pragma unroll
            for (int reg = 0; reg < 4; ++reg){
              float d = acc[k2][mt][nt][reg];   // f = mt*16 + quad*4 + reg
              s = fmaf(d, d, s);
            }
          s += __shfl_xor(s, 16);
          s += __shfl_xor(s, 32);               // sum over all 32 f
          if (quad == 0) sqs[nt*16 + l15][w][k] = s;
        }
      }
    }
  }
  __syncthreads();

  // ---- softmax over key heads + attn @ V  (thread = (row, q)) ----
  {
    const int r = t >> 3, q = t & 7;
    float lg[8];
    #pragma unroll
    for (int k = 0; k < 8; ++k) lg[k] = sqs[r][q][k] * -0.17677669529663687f; // -1/sqrt(32)
    float mx = lg[0];
    #pragma unroll
    for (int k = 1; k < 8; ++k) mx = fmaxf(mx, lg[k]);
    float e[8], sum = 0.f;
    #pragma unroll
    for (int k = 0; k < 8; ++k){ e[k] = __expf(lg[k] - mx); sum += e[k]; }
    const float inv = 1.0f / sum;
    #pragma unroll
    for (int k = 0; k < 8; ++k) e[k] *= inv;

    #pragma unroll
    for (int dc = 0; dc < 4; ++dc){
      const int d0 = dc*8;
      float o[8] = {0.f,0.f,0.f,0.f,0.f,0.f,0.f,0.f};
      #pragma unroll
      for (int k = 0; k < 8; ++k){
        i32x4 v = *(const i32x4*)&Vs[r][k*32 + d0];
        const float a = e[k];
        #pragma unroll
        for (int p = 0; p < 4; ++p){
          unsigned int u = (unsigned int)v[p];
          o[2*p    ] = fmaf(a, __builtin_bit_cast(float, u << 16),          o[2*p    ]);
          o[2*p + 1] = fmaf(a, __builtin_bit_cast(float, u & 0xFFFF0000u),  o[2*p + 1]);
        }
      }
      i32x4 pkv;
      #pragma unroll
      for (int p = 0; p < 4; ++p)
        pkv[p] = (int)pk2(o[2*p], o[2*p + 1]);
      *(i32x4*)&ao[r][q*32 + d0] = pkv;
    }
  }
  __syncthreads();   // after this, xs and Vs are dead -> hs overlay is safe

  // ---- h = ao @ Wout + b_out + x(fp32 re-read)  -> hs (fp32) ----
  {
    f32x4 acc[4][2];
    #pragma unroll
    for (int mt = 0; mt < 4; ++mt)
      #pragma unroll
      for (int nt = 0; nt < 2; ++nt) acc[mt][nt] = f32x4{0.f,0.f,0.f,0.f};
    #pragma unroll
    for (int kk = 0; kk < 8; ++kk){
      const int c0 = kk*32 + quad*8;
      bf16x8 a[4], bfr[2];
      #pragma unroll
      for (int mt = 0; mt < 4; ++mt) a[mt] = ldfrag(&ao[mt*16 + l15][c0]);
      #pragma unroll
      for (int nt = 0; nt < 2; ++nt){
        const int n = w*32 + nt*16 + l15;
        bfr[nt] = __builtin_bit_cast(bf16x8, *(const i32x4*)(WoutT + (size_t)n*256 + c0));
      }
      #pragma unroll
      for (int mt = 0; mt < 4; ++mt)
        #pragma unroll
        for (int nt = 0; nt < 2; ++nt)
          acc[mt][nt] = __builtin_amdgcn_mfma_f32_16x16x32_bf16(a[mt], bfr[nt], acc[mt][nt], 0, 0, 0);
    }
    #pragma unroll
    for (int nt = 0; nt < 2; ++nt){
      const int col = w*32 + nt*16 + l15;
      const float bo = b_out[col];
      #pragma unroll
      for (int mt = 0; mt < 4; ++mt)
        #pragma unroll
        for (int reg = 0; reg < 4; ++reg){
          const int row = mt*16 + quad*4 + reg;
          hs[row][col] = acc[mt][nt][reg] + bo + x[(rowbase + row)*256 + col];
        }
    }
  }
  __syncthreads();

  // ---- LayerNorm per row (fp32), coalesced fp32 store ----
  {
    #pragma unroll
    for (int rr = 0; rr < 8; ++rr){
      const int r = w*8 + rr;
      const int c = lane*4;
      f32x4 hv = *(const f32x4*)&hs[r][c];
      float s  = hv[0] + hv[1] + hv[2] + hv[3];
      float s2 = hv[0]*hv[0] + hv[1]*hv[1] + hv[2]*hv[2] + hv[3]*hv[3];
      #pragma unroll
      for (int off = 1; off < 64; off <<= 1){
        s  += __shfl_xor(s,  off);
        s2 += __shfl_xor(s2, off);
      }
      const float mu  = s  * (1.0f/256.0f);
      const float var = s2 * (1.0f/256.0f) - mu*mu;
      const float rs  = rsqrtf(var + 1e-5f);
      f32x4 gv = *(const f32x4*)(gamma + c);
      f32x4 bv = *(const f32x4*)(beta  + c);
      f32x4 y;
      y[0] = (hv[0] - mu)*rs*gv[0] + bv[0];
      y[1] = (hv[1] - mu)*rs*gv[1] + bv[1];
      y[2] = (hv[2] - mu)*rs*gv[2] + bv[2];
      y[3] = (hv[3] - mu)*rs*gv[3] + bv[3];
      *(f32x4*)(out + (rowbase + r)*256 + c) = y;
    }
  }
}

extern "C" void kernel_launch(void* const* d_in, const int* in_sizes, int n_in,
                              void* d_out, int out_size, void* d_ws, size_t ws_size,
                              hipStream_t stream)
{
  const float* x     = (const float*)d_in[0];
  const float* Wq    = (const float*)d_in[1];
  const float* Wk    = (const float*)d_in[2];
  const float* Wv    = (const float*)d_in[3];
  const float* Wout  = (const float*)d_in[4];
  const float* b_out = (const float*)d_in[5];
  const float* L     = (const float*)d_in[6];
  const float* gamma = (const float*)d_in[7];
  const float* beta  = (const float*)d_in[8];
  u16* ws = (u16*)d_ws;

  geo_prep<<<96, 256, 0, stream>>>(Wq, Wk, Wv, Wout, L, ws);
  geo_fused<<<1024, 512, 0, stream>>>(x, ws, ws + 524288, ws + 589824,
                                      b_out, gamma, beta, (float*)d_out);
}